// Round 3
// baseline (308.204 us; speedup 1.0000x reference)
//
#include <hip/hip_runtime.h>
#include <cstdint>

#define D_DIM 768
#define BM 256
#define BN 256
#define BK 64
#define NT 12                        // D_DIM / BK
#define ABYTES (BM * BK)             // 16 KB
#define SLOT   (BM * BK + BN * BK)   // 32 KB per ring slot
#define NBX 32                       // Nx / BM
#define NBY 64                       // Ny / BN

typedef int   intx8    __attribute__((ext_vector_type(8)));
typedef float floatx16 __attribute__((ext_vector_type(16)));

#define SCALE_ONE 0x7F7F7F7F  // E8M0 127 = 2^0 in every byte

// ---- helpers ----------------------------------------------------------------

__device__ inline void lds_load16(const void* g, void* lds) {
  __builtin_amdgcn_global_load_lds(
      (const __attribute__((address_space(1))) unsigned int*)g,
      (__attribute__((address_space(3))) unsigned int*)lds,
      16, 0, 0);
}

__device__ inline intx8 ldfrag(const unsigned char* p, int o0, int o1) {
  intx8 r;
  *(int4*)&r       = *(const int4*)(p + o0);
  *((int4*)&r + 1) = *(const int4*)(p + o1);
  return r;
}

// ---- kernel 1: row L2 norm + normalize + cast to fp8 e4m3 (both inputs) -----

__global__ __launch_bounds__(256) void norm_cast_kernel(
    const float* __restrict__ EX, const float* __restrict__ EY,
    unsigned int* __restrict__ XO, unsigned int* __restrict__ YO, int Nx) {
  int row = blockIdx.x * 4 + (threadIdx.x >> 6);
  int lane = threadIdx.x & 63;
  const float* X = (row < Nx) ? EX : EY;
  unsigned int* Y = (row < Nx) ? XO : YO;
  int r = (row < Nx) ? row : (row - Nx);
  const float4* xr = (const float4*)(X + (size_t)r * D_DIM);
  float4 a = xr[lane];
  float4 b = xr[lane + 64];
  float4 c = xr[lane + 128];
  float ss = a.x*a.x + a.y*a.y + a.z*a.z + a.w*a.w
           + b.x*b.x + b.y*b.y + b.z*b.z + b.w*b.w
           + c.x*c.x + c.y*c.y + c.z*c.z + c.w*c.w;
  #pragma unroll
  for (int off = 32; off > 0; off >>= 1) ss += __shfl_xor(ss, off, 64);
  float s = 1.0f / fmaxf(sqrtf(ss), 1e-8f);
  unsigned int* yr = Y + (size_t)r * (D_DIM / 4);
  int d;
  d = __builtin_amdgcn_cvt_pk_fp8_f32(a.x * s, a.y * s, 0, false);
  d = __builtin_amdgcn_cvt_pk_fp8_f32(a.z * s, a.w * s, d, true);
  yr[lane] = (unsigned int)d;
  d = __builtin_amdgcn_cvt_pk_fp8_f32(b.x * s, b.y * s, 0, false);
  d = __builtin_amdgcn_cvt_pk_fp8_f32(b.z * s, b.w * s, d, true);
  yr[lane + 64] = (unsigned int)d;
  d = __builtin_amdgcn_cvt_pk_fp8_f32(c.x * s, c.y * s, 0, false);
  d = __builtin_amdgcn_cvt_pk_fp8_f32(c.z * s, c.w * s, d, true);
  yr[lane + 128] = (unsigned int)d;
}

// ---- kernel 2: MX-fp8 MFMA GEMM (S = A . B^T) fused with per-row max --------
//
// m201-shaped: 256x256 tile, 8 waves (2m x 4n), wave tile 128x64 = acc[4][2]
// of 32x32, BK=64, 3-slot LDS ring (96 KB, 1 block/CU, 2 waves/SIMD), ONE raw
// s_barrier per K-tile, counted s_waitcnt vmcnt(4) (never 0 mid-loop),
// 2-tile-ahead prefetch.
//
// R2 lesson (conflicts 3x): 64-B LDS rows give only a 2-bit swizzle key ->
// reads hit 4 of 8 slot positions -> 2x LDS serialization. Fix: PAIRED-ROW
// layout. Physical rows are 128 B holding logical rows {2p, 2p+1}; chunk c of
// logical row r lives at phys slot ((r&1)*4 + c) ^ (p&7), p = r>>1. A wave64
// b128 frag read (r = base+l31, c in {2h, 2h+1}) hits all 8 slot positions
// exactly 8x each = conflict-minimal.
// Stager inverse (deposit is linear, 1024 B = 8 phys rows = 16 logical rows):
// lane q lands at phys row (q>>3), slot q&7, so its GLOBAL source must be
// ls = (q&7) ^ (q>>3); row = R0 + 2*(q>>3) + (ls>>2); chunk = ls&3.
// (Verified algebraically: reader(r,c) == stager slot for all q.)
//
// Ring safety (1 barrier/iter): STAGE(t+2) -> slot (t-1)%3, whose ds_reads
// were consumed by COMPUTE(t-1)'s MFMAs (lgkmcnt) before any wave reached
// barrier(t). vmcnt(4): outstanding at iter t = tiles {t, t+1} (4 loads
// each); wait-to-4 retires exactly tile t (FIFO). vmcnt precedes barrier, so
// every wave's staging is globally visible-complete after the barrier.
//
// R1 lesson: no full unroll (spill); rolled x3 for static slot indices.
// Plain __launch_bounds__(512): the (512,2) form capped VGPR at 128 in R1.

#define STAGE(SL, KO) do {                                                     \
    unsigned char* dst_ = lds + (SL) * SLOT + wave * 2048;                     \
    lds_load16(gA + (KO),       dst_);                                         \
    lds_load16(gA + (KO) + g16, dst_ + 1024);                                  \
    lds_load16(gB + (KO),       dst_ + ABYTES);                                \
    lds_load16(gB + (KO) + g16, dst_ + ABYTES + 1024);                         \
  } while (0)

#define MFMA(d, va, vb)                                                        \
  d = __builtin_amdgcn_mfma_scale_f32_32x32x64_f8f6f4(                         \
      va, vb, d, 0, 0, 0, SCALE_ONE, 0, SCALE_ONE)

#define COMPUTE(SL) do {                                                       \
    const unsigned char* bufA_ = lds + (SL) * SLOT + wm * 8192;                \
    const unsigned char* bufB_ = lds + (SL) * SLOT + ABYTES + wn * 4096;       \
    intx8 a0 = ldfrag(bufA_,        o0, o1);                                   \
    intx8 a1 = ldfrag(bufA_ + 2048, o0, o1);                                   \
    intx8 a2 = ldfrag(bufA_ + 4096, o0, o1);                                   \
    intx8 a3 = ldfrag(bufA_ + 6144, o0, o1);                                   \
    intx8 b0 = ldfrag(bufB_,        o0, o1);                                   \
    intx8 b1 = ldfrag(bufB_ + 2048, o0, o1);                                   \
    __builtin_amdgcn_s_setprio(1);                                             \
    MFMA(acc[0][0], a0, b0);                                                   \
    MFMA(acc[1][0], a1, b0);                                                   \
    MFMA(acc[2][0], a2, b0);                                                   \
    MFMA(acc[3][0], a3, b0);                                                   \
    MFMA(acc[0][1], a0, b1);                                                   \
    MFMA(acc[1][1], a1, b1);                                                   \
    MFMA(acc[2][1], a2, b1);                                                   \
    MFMA(acc[3][1], a3, b1);                                                   \
    __builtin_amdgcn_s_setprio(0);                                             \
  } while (0)

#define WAITB(VMC) do {                                                        \
    asm volatile("s_waitcnt vmcnt(" #VMC ")" ::: "memory");                    \
    __builtin_amdgcn_s_barrier();                                              \
  } while (0)

__global__ __launch_bounds__(512) void gemm_max_kernel(
    const unsigned char* __restrict__ A,   // exn [Nx x 768] fp8
    const unsigned char* __restrict__ B,   // eyn [Ny x 768] fp8
    float* __restrict__ partial,           // [ncb][Nx]
    int Nx) {
  __shared__ unsigned char lds[3 * SLOT];  // 96 KB ring
  __shared__ float red[4][BM];             // 4 KB

  const int tid  = threadIdx.x;
  const int wave = tid >> 6;       // 0..7
  const int lane = tid & 63;
  const int wm = wave >> 2;        // 0..1: 128-row half
  const int wn = wave & 3;         // 0..3: 64-col quarter
  const int l31 = lane & 31;
  const int h   = lane >> 5;       // half-wave: K 32B-half selector

  // T1: supertile XCD swizzle. Grid 32x64 = 2048 blocks, 8 XCDs; concurrent
  // 32 blocks per XCD (1 block/CU) form one 8(bx) x 4(by) supertile:
  // 8 A-panels + 4 B-panels = 2.3 MB < 4 MB XCD L2. Bijective.
  const int lid    = blockIdx.x;
  const int xcd    = lid & 7;
  const int idx    = lid >> 3;       // 0..255
  const int g      = idx >> 5;       // 0..7
  const int within = idx & 31;
  const int st     = g * 8 + xcd;    // 0..63
  const int bx = (st & 3) * 8 + (within & 7);    // 0..31
  const int by = (st >> 2) * 4 + (within >> 3);  // 0..63

  const int bm0 = bx * BM;
  const int bn0 = by * BN;

  floatx16 acc[4][2];
  #pragma unroll
  for (int m = 0; m < 4; ++m)
    #pragma unroll
    for (int n = 0; n < 2; ++n)
      acc[m][n] = (floatx16)(0.f);

  // reader-side paired-row addresses (see header comment):
  // addr = rowgroup_base + (l31>>1)*128 + ((((l31&1)*4 + c) ^ ((l31>>1)&7))*16
  const int key  = (l31 >> 1) & 7;
  const int lrow = (l31 >> 1) * 128;
  const int c0   = 2 * h;
  const int o0 = lrow + ((((l31 & 1) << 2) | c0)       ^ key) * 16;
  const int o1 = lrow + ((((l31 & 1) << 2) | (c0 + 1)) ^ key) * 16;

  // stager: each wave deposits 32 A rows + 32 B rows per tile (2 + 2 loads).
  const int ls   = (lane & 7) ^ (lane >> 3);
  const int srow = 2 * (lane >> 3) + (ls >> 2);
  const int sc   = ls & 3;
  const unsigned char* gA = A + (size_t)(bm0 + wave * 32 + srow) * D_DIM + sc * 16;
  const unsigned char* gB = B + (size_t)(bn0 + wave * 32 + srow) * D_DIM + sc * 16;
  const size_t g16 = (size_t)16 * D_DIM;

  STAGE(0, 0);
  STAGE(1, BK);

  #pragma unroll 1
  for (int t0 = 0; t0 < 9; t0 += 3) {
    const int kb = t0 * BK;
    WAITB(4); STAGE(2, kb + 2 * BK); COMPUTE(0);
    WAITB(4); STAGE(0, kb + 3 * BK); COMPUTE(1);
    WAITB(4); STAGE(1, kb + 4 * BK); COMPUTE(2);
  }
  WAITB(4); STAGE(2, 11 * BK); COMPUTE(0);   // t=9
  WAITB(4);                    COMPUTE(1);   // t=10
  WAITB(0);                    COMPUTE(2);   // t=11 (drain)

  // epilogue: per-row max over this block's 256 columns.
  // C/D (32x32): col = l31 (+n*32 + wn*64), row = (reg&3)+8*(reg>>2)+4*h
  // (+m*32 + wm*128)
  #pragma unroll
  for (int m = 0; m < 4; ++m) {
    #pragma unroll
    for (int reg = 0; reg < 16; ++reg) {
      float v = fmaxf(acc[m][0][reg], acc[m][1][reg]);
      #pragma unroll
      for (int off = 1; off < 32; off <<= 1)
        v = fmaxf(v, __shfl_xor(v, off, 64));   // reduce within each 32-half
      if (l31 == 0) {
        int r = wm * 128 + m * 32 + (reg & 3) + 8 * (reg >> 2) + 4 * h;
        red[wn][r] = v;
      }
    }
  }
  __syncthreads();
  if (tid < BM) {
    float mv = fmaxf(fmaxf(red[0][tid], red[1][tid]),
                     fmaxf(red[2][tid], red[3][tid]));
    partial[(size_t)by * Nx + bm0 + tid] = mv;
  }
}

// ---- kernel 3: row max over column blocks + halfnormal transform + block sum

__global__ __launch_bounds__(256) void rowmax_kernel(
    const float* __restrict__ partial, float* __restrict__ bsum, int Nx, int ncb) {
  __shared__ float sdata[4];
  int r = blockIdx.x * blockDim.x + threadIdx.x;
  float m = -1e30f;
  for (int cb = 0; cb < ncb; ++cb)
    m = fmaxf(m, partial[(size_t)cb * Nx + r]);
  float x = 1.0f - m;
  const float logc = -0.22579135264472744f;  // 0.5*log(2/pi), sigma=1
  float l = logc - 0.5f * x * x;
  float t = -__expf(l) * l;
  #pragma unroll
  for (int off = 32; off > 0; off >>= 1) t += __shfl_xor(t, off, 64);
  int wave = threadIdx.x >> 6;
  int lane = threadIdx.x & 63;
  if (lane == 0) sdata[wave] = t;
  __syncthreads();
  if (threadIdx.x == 0)
    bsum[blockIdx.x] = sdata[0] + sdata[1] + sdata[2] + sdata[3];
}

// ---- kernel 4: final sum of block partials -> out[0], out[1] ----------------

__global__ __launch_bounds__(64) void final_kernel(
    const float* __restrict__ bsum, float* __restrict__ out, int nb) {
  int lane = threadIdx.x;
  float s = (lane < nb) ? bsum[lane] : 0.f;
  #pragma unroll
  for (int off = 32; off > 0; off >>= 1) s += __shfl_xor(s, off, 64);
  if (lane == 0) { out[0] = s; out[1] = s; }
}

// ---- launch -----------------------------------------------------------------

extern "C" void kernel_launch(void* const* d_in, const int* in_sizes, int n_in,
                              void* d_out, int out_size, void* d_ws, size_t ws_size,
                              hipStream_t stream) {
  const float* ex = (const float*)d_in[0];
  const float* ey = (const float*)d_in[1];
  const int Nx = in_sizes[0] / D_DIM;   // 8192
  const int Ny = in_sizes[1] / D_DIM;   // 16384
  const int ncb = Ny / BN;              // 64

  char* ws = (char*)d_ws;
  unsigned char* exn = (unsigned char*)ws;                                   // Nx*768 fp8
  unsigned char* eyn = exn + (size_t)Nx * D_DIM;                             // Ny*768 fp8
  float* partial = (float*)(ws + (size_t)(Nx + Ny) * D_DIM);                 // ncb*Nx f32
  float* bsum    = partial + (size_t)ncb * Nx;                               // 32 f32

  norm_cast_kernel<<<(Nx + Ny) / 4, 256, 0, stream>>>(
      ex, ey, (unsigned int*)exn, (unsigned int*)eyn, Nx);
  gemm_max_kernel<<<NBX * NBY, 512, 0, stream>>>(exn, eyn, partial, Nx);
  rowmax_kernel<<<Nx / 256, 256, 0, stream>>>(partial, bsum, Nx, ncb);
  final_kernel<<<1, 64, 0, stream>>>(bsum, (float*)d_out, Nx / 256);
}

// Round 4
// 304.677 us; speedup vs baseline: 1.0116x; 1.0116x over previous
//
#include <hip/hip_runtime.h>
#include <cstdint>

#define D_DIM 768
#define BM 256
#define BN 256
#define BK 64
#define NT 12                        // D_DIM / BK
#define ABYTES (BM * BK)             // 16 KB
#define SLOT   (BM * BK + BN * BK)   // 32 KB per ring slot
#define NBX 32                       // Nx / BM
#define NBY 64                       // Ny / BN

typedef int   intx8    __attribute__((ext_vector_type(8)));
typedef float floatx16 __attribute__((ext_vector_type(16)));

#define SCALE_ONE 0x7F7F7F7F  // E8M0 127 = 2^0 in every byte

// ---- helpers ----------------------------------------------------------------

__device__ inline void lds_load16(const void* g, void* lds) {
  __builtin_amdgcn_global_load_lds(
      (const __attribute__((address_space(1))) unsigned int*)g,
      (__attribute__((address_space(3))) unsigned int*)lds,
      16, 0, 0);
}

__device__ inline intx8 ldfrag(const unsigned char* p, int o0, int o1) {
  intx8 r;
  *(int4*)&r       = *(const int4*)(p + o0);
  *((int4*)&r + 1) = *(const int4*)(p + o1);
  return r;
}

// ---- kernel 1: row L2 norm + normalize + cast to fp8 e4m3 (both inputs) -----

__global__ __launch_bounds__(256) void norm_cast_kernel(
    const float* __restrict__ EX, const float* __restrict__ EY,
    unsigned int* __restrict__ XO, unsigned int* __restrict__ YO, int Nx) {
  int row = blockIdx.x * 4 + (threadIdx.x >> 6);
  int lane = threadIdx.x & 63;
  const float* X = (row < Nx) ? EX : EY;
  unsigned int* Y = (row < Nx) ? XO : YO;
  int r = (row < Nx) ? row : (row - Nx);
  const float4* xr = (const float4*)(X + (size_t)r * D_DIM);
  float4 a = xr[lane];
  float4 b = xr[lane + 64];
  float4 c = xr[lane + 128];
  float ss = a.x*a.x + a.y*a.y + a.z*a.z + a.w*a.w
           + b.x*b.x + b.y*b.y + b.z*b.z + b.w*b.w
           + c.x*c.x + c.y*c.y + c.z*c.z + c.w*c.w;
  #pragma unroll
  for (int off = 32; off > 0; off >>= 1) ss += __shfl_xor(ss, off, 64);
  float s = 1.0f / fmaxf(sqrtf(ss), 1e-8f);
  unsigned int* yr = Y + (size_t)r * (D_DIM / 4);
  int d;
  d = __builtin_amdgcn_cvt_pk_fp8_f32(a.x * s, a.y * s, 0, false);
  d = __builtin_amdgcn_cvt_pk_fp8_f32(a.z * s, a.w * s, d, true);
  yr[lane] = (unsigned int)d;
  d = __builtin_amdgcn_cvt_pk_fp8_f32(b.x * s, b.y * s, 0, false);
  d = __builtin_amdgcn_cvt_pk_fp8_f32(b.z * s, b.w * s, d, true);
  yr[lane + 64] = (unsigned int)d;
  d = __builtin_amdgcn_cvt_pk_fp8_f32(c.x * s, c.y * s, 0, false);
  d = __builtin_amdgcn_cvt_pk_fp8_f32(c.z * s, c.w * s, d, true);
  yr[lane + 128] = (unsigned int)d;
}

// ---- kernel 2: MX-fp8 MFMA GEMM (S = A . B^T) fused with per-row max --------
//
// R3 geometry kept verbatim (verified: paired-row swizzle -> conflicts back
// to 9.4M floor; absmax 0): 256x256 tile, 8 waves (2m x 4n), wave tile
// 128x64 = acc[4][2] of 32x32x64, BK=64, 3-slot ring, T1 supertile swizzle.
//
// R3 lesson (m230/m233 regime gate, re-learned the hard way): coarse
// 1-phase-per-tile + counted vmcnt = null. All 8 waves barrier-aligned ->
// per-iter LDS read burst (~1150 cyc/CU) serializes against the MFMA burst
// (~1100 cyc/CU). Fix = m201 fine-phase schedule: per K-tile, TWO phases of
// {4 ds_read frags || 2-load stage -> barrier -> lgkmcnt(0) -> setprio ->
// 4 MFMA -> setprio -> barrier}. Phase MFMA time ~69 CU-cyc = m201's phase
// thickness. b0/b1 live across the phase pair (peak frag liveness 4 < R3's
// 6 -> arch VGPR <= 128, stays on the 2-waves/SIMD side of the 256 cliff).
//
// Waits: vmcnt(4) once per tile, at end of P2 after staging B-half of t+2.
// Outstanding there = t+1's 4 + t+2's 4 = 8 -> retire exactly t+1 (FIFO),
// keep t+2 in flight. Never 0 mid-loop. Tile 10 drains t=11's loads
// (vmcnt(0), issued 2 tiles back, ~free). Ring safety: stage(t+2) writes
// slot (t-1)%3, whose ds_reads retired via lgkmcnt(0) before t-1's final
// barrier; stage is issued after that barrier.

#define STAGE_A(SL, KO) do {                                                   \
    unsigned char* dst_ = lds + (SL) * SLOT + wave * 2048;                     \
    lds_load16(gA + (KO),       dst_);                                         \
    lds_load16(gA + (KO) + g16, dst_ + 1024);                                  \
  } while (0)

#define STAGE_B(SL, KO) do {                                                   \
    unsigned char* dst_ = lds + (SL) * SLOT + ABYTES + wave * 2048;            \
    lds_load16(gB + (KO),       dst_);                                         \
    lds_load16(gB + (KO) + g16, dst_ + 1024);                                  \
  } while (0)

#define MFMA(d, va, vb)                                                        \
  d = __builtin_amdgcn_mfma_scale_f32_32x32x64_f8f6f4(                         \
      va, vb, d, 0, 0, 0, SCALE_ONE, 0, SCALE_ONE)

#define VMW(N) asm volatile("s_waitcnt vmcnt(" #N ")" ::: "memory")

#define TILE(SL, PSL, KO, STG, VM) do {                                        \
    const unsigned char* bA_ = lds + (SL) * SLOT + wm * 8192;                  \
    const unsigned char* bB_ = lds + (SL) * SLOT + ABYTES + wn * 4096;         \
    /* ---- phase 1: frags + A-half stage, quadrant acc[0..1][*] ---- */       \
    a0 = ldfrag(bA_,        o0, o1);                                           \
    a1 = ldfrag(bA_ + 2048, o0, o1);                                           \
    b0 = ldfrag(bB_,        o0, o1);                                           \
    b1 = ldfrag(bB_ + 2048, o0, o1);                                           \
    if (STG) STAGE_A(PSL, KO);                                                 \
    __builtin_amdgcn_s_barrier();                                              \
    asm volatile("s_waitcnt lgkmcnt(0)" ::: "memory");                         \
    __builtin_amdgcn_sched_barrier(0);                                         \
    __builtin_amdgcn_s_setprio(1);                                             \
    MFMA(acc[0][0], a0, b0);  MFMA(acc[1][0], a1, b0);                         \
    MFMA(acc[0][1], a0, b1);  MFMA(acc[1][1], a1, b1);                         \
    __builtin_amdgcn_s_setprio(0);                                             \
    __builtin_amdgcn_s_barrier();                                              \
    /* ---- phase 2: frags + B-half stage, quadrant acc[2..3][*] ---- */       \
    a2 = ldfrag(bA_ + 4096, o0, o1);                                           \
    a3 = ldfrag(bA_ + 6144, o0, o1);                                           \
    if (STG) STAGE_B(PSL, KO);                                                 \
    VM;                                                                        \
    __builtin_amdgcn_s_barrier();                                              \
    asm volatile("s_waitcnt lgkmcnt(0)" ::: "memory");                         \
    __builtin_amdgcn_sched_barrier(0);                                         \
    __builtin_amdgcn_s_setprio(1);                                             \
    MFMA(acc[2][0], a2, b0);  MFMA(acc[3][0], a3, b0);                         \
    MFMA(acc[2][1], a2, b1);  MFMA(acc[3][1], a3, b1);                         \
    __builtin_amdgcn_s_setprio(0);                                             \
    __builtin_amdgcn_s_barrier();                                              \
  } while (0)

__global__ __launch_bounds__(512) void gemm_max_kernel(
    const unsigned char* __restrict__ A,   // exn [Nx x 768] fp8
    const unsigned char* __restrict__ B,   // eyn [Ny x 768] fp8
    float* __restrict__ partial,           // [ncb][Nx]
    int Nx) {
  __shared__ unsigned char lds[3 * SLOT];  // 96 KB ring
  __shared__ float red[4][BM];             // 4 KB

  const int tid  = threadIdx.x;
  const int wave = tid >> 6;       // 0..7
  const int lane = tid & 63;
  const int wm = wave >> 2;        // 0..1: 128-row half
  const int wn = wave & 3;         // 0..3: 64-col quarter
  const int l31 = lane & 31;
  const int h   = lane >> 5;       // half-wave: K 32B-half selector

  // T1: supertile XCD swizzle (unchanged, R3-verified). Concurrent 32 blocks
  // per XCD form an 8(bx) x 4(by) supertile: ~2.3 MB < 4 MB XCD L2.
  const int lid    = blockIdx.x;
  const int xcd    = lid & 7;
  const int idx    = lid >> 3;       // 0..255
  const int g      = idx >> 5;       // 0..7
  const int within = idx & 31;
  const int st     = g * 8 + xcd;    // 0..63
  const int bx = (st & 3) * 8 + (within & 7);    // 0..31
  const int by = (st >> 2) * 4 + (within >> 3);  // 0..63

  const int bm0 = bx * BM;
  const int bn0 = by * BN;

  floatx16 acc[4][2];
  #pragma unroll
  for (int m = 0; m < 4; ++m)
    #pragma unroll
    for (int n = 0; n < 2; ++n)
      acc[m][n] = (floatx16)(0.f);

  // reader-side paired-row addresses (R3-verified):
  // addr = (l31>>1)*128 + ((((l31&1)*4 + c) ^ ((l31>>1)&7))*16, c in {2h,2h+1}
  const int key  = (l31 >> 1) & 7;
  const int lrow = (l31 >> 1) * 128;
  const int c0   = 2 * h;
  const int o0 = lrow + ((((l31 & 1) << 2) | c0)       ^ key) * 16;
  const int o1 = lrow + ((((l31 & 1) << 2) | (c0 + 1)) ^ key) * 16;

  // stager (R3-verified inverse): lane q -> phys row q>>3, slot q&7;
  // global source ls = (q&7)^(q>>3); row = 2*(q>>3)+(ls>>2); chunk = ls&3.
  const int ls   = (lane & 7) ^ (lane >> 3);
  const int srow = 2 * (lane >> 3) + (ls >> 2);
  const int sc   = ls & 3;
  const unsigned char* gA = A + (size_t)(bm0 + wave * 32 + srow) * D_DIM + sc * 16;
  const unsigned char* gB = B + (size_t)(bn0 + wave * 32 + srow) * D_DIM + sc * 16;
  const size_t g16 = (size_t)16 * D_DIM;

  intx8 a0, a1, a2, a3, b0, b1;

  STAGE_A(0, 0);      STAGE_B(0, 0);       // tile 0
  STAGE_A(1, BK);     STAGE_B(1, BK);      // tile 1
  VMW(4);                                   // tile 0 resident, tile 1 in flight
  __builtin_amdgcn_s_barrier();

  #pragma unroll 1
  for (int t0 = 0; t0 < 9; t0 += 3) {
    const int kb = t0 * BK;
    TILE(0, 2, kb + 2 * BK, 1, VMW(4));
    TILE(1, 0, kb + 3 * BK, 1, VMW(4));
    TILE(2, 1, kb + 4 * BK, 1, VMW(4));
  }
  TILE(0, 2, 11 * BK, 1, VMW(4));          // t=9: stage tile 11
  TILE(1, 0, 0,       0, VMW(0));          // t=10: drain tile 11's loads
  TILE(2, 0, 0,       0, ((void)0));       // t=11

  // epilogue: per-row max over this block's 256 columns.
  // C/D (32x32): col = l31 (+n*32 + wn*64), row = (reg&3)+8*(reg>>2)+4*h
  // (+m*32 + wm*128)
  #pragma unroll
  for (int m = 0; m < 4; ++m) {
    #pragma unroll
    for (int reg = 0; reg < 16; ++reg) {
      float v = fmaxf(acc[m][0][reg], acc[m][1][reg]);
      #pragma unroll
      for (int off = 1; off < 32; off <<= 1)
        v = fmaxf(v, __shfl_xor(v, off, 64));   // reduce within each 32-half
      if (l31 == 0) {
        int r = wm * 128 + m * 32 + (reg & 3) + 8 * (reg >> 2) + 4 * h;
        red[wn][r] = v;
      }
    }
  }
  __syncthreads();
  if (tid < BM) {
    float mv = fmaxf(fmaxf(red[0][tid], red[1][tid]),
                     fmaxf(red[2][tid], red[3][tid]));
    partial[(size_t)by * Nx + bm0 + tid] = mv;
  }
}

// ---- kernel 3: row max over column blocks + halfnormal transform + block sum

__global__ __launch_bounds__(256) void rowmax_kernel(
    const float* __restrict__ partial, float* __restrict__ bsum, int Nx, int ncb) {
  __shared__ float sdata[4];
  int r = blockIdx.x * blockDim.x + threadIdx.x;
  float m = -1e30f;
  for (int cb = 0; cb < ncb; ++cb)
    m = fmaxf(m, partial[(size_t)cb * Nx + r]);
  float x = 1.0f - m;
  const float logc = -0.22579135264472744f;  // 0.5*log(2/pi), sigma=1
  float l = logc - 0.5f * x * x;
  float t = -__expf(l) * l;
  #pragma unroll
  for (int off = 32; off > 0; off >>= 1) t += __shfl_xor(t, off, 64);
  int wave = threadIdx.x >> 6;
  int lane = threadIdx.x & 63;
  if (lane == 0) sdata[wave] = t;
  __syncthreads();
  if (threadIdx.x == 0)
    bsum[blockIdx.x] = sdata[0] + sdata[1] + sdata[2] + sdata[3];
}

// ---- kernel 4: final sum of block partials -> out[0], out[1] ----------------

__global__ __launch_bounds__(64) void final_kernel(
    const float* __restrict__ bsum, float* __restrict__ out, int nb) {
  int lane = threadIdx.x;
  float s = (lane < nb) ? bsum[lane] : 0.f;
  #pragma unroll
  for (int off = 32; off > 0; off >>= 1) s += __shfl_xor(s, off, 64);
  if (lane == 0) { out[0] = s; out[1] = s; }
}

// ---- launch -----------------------------------------------------------------

extern "C" void kernel_launch(void* const* d_in, const int* in_sizes, int n_in,
                              void* d_out, int out_size, void* d_ws, size_t ws_size,
                              hipStream_t stream) {
  const float* ex = (const float*)d_in[0];
  const float* ey = (const float*)d_in[1];
  const int Nx = in_sizes[0] / D_DIM;   // 8192
  const int Ny = in_sizes[1] / D_DIM;   // 16384
  const int ncb = Ny / BN;              // 64

  char* ws = (char*)d_ws;
  unsigned char* exn = (unsigned char*)ws;                                   // Nx*768 fp8
  unsigned char* eyn = exn + (size_t)Nx * D_DIM;                             // Ny*768 fp8
  float* partial = (float*)(ws + (size_t)(Nx + Ny) * D_DIM);                 // ncb*Nx f32
  float* bsum    = partial + (size_t)ncb * Nx;                               // 32 f32

  norm_cast_kernel<<<(Nx + Ny) / 4, 256, 0, stream>>>(
      ex, ey, (unsigned int*)exn, (unsigned int*)eyn, Nx);
  gemm_max_kernel<<<NBX * NBY, 512, 0, stream>>>(exn, eyn, partial, Nx);
  rowmax_kernel<<<Nx / 256, 256, 0, stream>>>(partial, bsum, Nx, ncb);
  final_kernel<<<1, 64, 0, stream>>>(bsum, (float*)d_out, Nx / 256);
}

// Round 6
// 303.727 us; speedup vs baseline: 1.0147x; 1.0031x over previous
//
#include <hip/hip_runtime.h>
#include <cstdint>

#define D_DIM 768
#define BM 256
#define BN 256
#define BK 64
#define NT 12                        // D_DIM / BK
#define ABYTES (BM * BK)             // 16 KB
#define SLOT   (BM * BK + BN * BK)   // 32 KB per ring slot
#define NBX 32                       // Nx / BM
#define NBY 64                       // Ny / BN

typedef int   intx4    __attribute__((ext_vector_type(4)));
typedef int   intx8    __attribute__((ext_vector_type(8)));
typedef float floatx16 __attribute__((ext_vector_type(16)));
typedef const __attribute__((address_space(3))) unsigned char* lds3;

#define SCALE_ONE 0x7F7F7F7F  // E8M0 127 = 2^0 in every byte

// ---- helpers ----------------------------------------------------------------

__device__ inline void lds_load16(const void* g, void* lds) {
  __builtin_amdgcn_global_load_lds(
      (const __attribute__((address_space(1))) unsigned int*)g,
      (__attribute__((address_space(3))) unsigned int*)lds,
      16, 0, 0);
}

__device__ inline intx8 cat8(intx4 lo, intx4 hi) {
  intx8 r;
  *(intx4*)&r       = lo;
  *((intx4*)&r + 1) = hi;
  return r;
}

// R4 lesson: compiler-visible ds_reads of the __shared__ object written by
// global_load_lds get a compiler-inserted s_waitcnt vmcnt(0) each (alias
// conservatism) -> the counted-vmcnt prefetch never existed. Fix: asm
// ds_read_b128 (invisible to the waitcnt pass).
// R5 lesson (NaN): the asm outputs were copied into an intx8 BEFORE any
// lgkmcnt wait -> copies read in-flight ds_read destinations -> garbage
// (0xFF = e4m3fn NaN). Fix: the lgkmcnt(0) wait asm takes every pending
// fragment as a "+v" operand (wait DEFINES them; all uses are data-dependent
// on the wait), intx8 built only after; sched_barrier(0) after (rule 18).
// Also restored "memory" clobbers on VMW/LGKM so global_load_lds builtins
// cannot cross the counted waits (R5's second hole).
#define DSR2(LO, HI, BASE, O0, O1)                                             \
  asm volatile("ds_read_b128 %0, %2\n\t"                                       \
               "ds_read_b128 %1, %3"                                           \
               : "=&v"(LO), "=&v"(HI)                                          \
               : "v"((BASE) + (O0)), "v"((BASE) + (O1)))

// ---- kernel 1: row L2 norm + normalize + cast to fp8 e4m3 (both inputs) -----

__global__ __launch_bounds__(256) void norm_cast_kernel(
    const float* __restrict__ EX, const float* __restrict__ EY,
    unsigned int* __restrict__ XO, unsigned int* __restrict__ YO, int Nx) {
  int row = blockIdx.x * 4 + (threadIdx.x >> 6);
  int lane = threadIdx.x & 63;
  const float* X = (row < Nx) ? EX : EY;
  unsigned int* Y = (row < Nx) ? XO : YO;
  int r = (row < Nx) ? row : (row - Nx);
  const float4* xr = (const float4*)(X + (size_t)r * D_DIM);
  float4 a = xr[lane];
  float4 b = xr[lane + 64];
  float4 c = xr[lane + 128];
  float ss = a.x*a.x + a.y*a.y + a.z*a.z + a.w*a.w
           + b.x*b.x + b.y*b.y + b.z*b.z + b.w*b.w
           + c.x*c.x + c.y*c.y + c.z*c.z + c.w*c.w;
  #pragma unroll
  for (int off = 32; off > 0; off >>= 1) ss += __shfl_xor(ss, off, 64);
  float s = 1.0f / fmaxf(sqrtf(ss), 1e-8f);
  unsigned int* yr = Y + (size_t)r * (D_DIM / 4);
  int d;
  d = __builtin_amdgcn_cvt_pk_fp8_f32(a.x * s, a.y * s, 0, false);
  d = __builtin_amdgcn_cvt_pk_fp8_f32(a.z * s, a.w * s, d, true);
  yr[lane] = (unsigned int)d;
  d = __builtin_amdgcn_cvt_pk_fp8_f32(b.x * s, b.y * s, 0, false);
  d = __builtin_amdgcn_cvt_pk_fp8_f32(b.z * s, b.w * s, d, true);
  yr[lane + 64] = (unsigned int)d;
  d = __builtin_amdgcn_cvt_pk_fp8_f32(c.x * s, c.y * s, 0, false);
  d = __builtin_amdgcn_cvt_pk_fp8_f32(c.z * s, c.w * s, d, true);
  yr[lane + 128] = (unsigned int)d;
}

// ---- kernel 2: MX-fp8 MFMA GEMM (S = A . B^T) fused with per-row max --------
//
// Geometry (R3/R4-verified, absmax 0): 256x256 tile, 8 waves (2m x 4n), wave
// tile 128x64 = acc[4][2] of 32x32x64 MX-fp8, BK=64, 3-slot ring, paired-row
// XOR swizzle (conflict floor 9.4M), T1 supertile XCD swizzle.
//
// Schedule: per K-tile, TWO phases of {asm ds_read frags || 2-load stage ->
// s_barrier -> lgkmcnt(0)["+v" frags] -> sched_barrier(0) -> combine ->
// setprio(1) 4x MFMA setprio(0) -> s_barrier}. vmcnt(4) once per tile (end
// of phase 2): outstanding there = tile(t+1) 4 + tile(t+2) 4 = 8 -> retires
// exactly t+1 (FIFO), keeps t+2 in flight. Never 0 mid-loop. The wait
// precedes the tile-final barrier, so after that barrier every wave's t+1
// DMA is LDS-visible; t+1's frag reads come after it. Ring safety:
// stage(t+2) overwrites slot (t-1)%3, consumed under lgkmcnt(0) before
// t-1's final barrier.

#define STAGE_A(SL, KO) do {                                                   \
    unsigned char* dst_ = lds + (SL) * SLOT + wave * 2048;                     \
    lds_load16(gA + (KO),       dst_);                                         \
    lds_load16(gA + (KO) + g16, dst_ + 1024);                                  \
  } while (0)

#define STAGE_B(SL, KO) do {                                                   \
    unsigned char* dst_ = lds + (SL) * SLOT + ABYTES + wave * 2048;            \
    lds_load16(gB + (KO),       dst_);                                         \
    lds_load16(gB + (KO) + g16, dst_ + 1024);                                  \
  } while (0)

#define MFMA(d, va, vb)                                                        \
  d = __builtin_amdgcn_mfma_scale_f32_32x32x64_f8f6f4(                         \
      va, vb, d, 0, 0, 0, SCALE_ONE, 0, SCALE_ONE)

#define VMW(N) asm volatile("s_waitcnt vmcnt(" #N ")" ::: "memory")

#define TILE(SL, PSL, KO, STG, VM) do {                                        \
    lds3 bA_ = L + (SL) * SLOT + wm * 8192;                                    \
    lds3 bB_ = L + (SL) * SLOT + ABYTES + wn * 4096;                           \
    intx4 a0l, a0h, a1l, a1h, a2l, a2h, a3l, a3h, b0l, b0h, b1l, b1h;          \
    /* ---- phase 1: frags + A-half stage, quadrant acc[0..1][*] ---- */       \
    DSR2(a0l, a0h, bA_,        o0, o1);                                        \
    DSR2(a1l, a1h, bA_ + 2048, o0, o1);                                        \
    DSR2(b0l, b0h, bB_,        o0, o1);                                        \
    DSR2(b1l, b1h, bB_ + 2048, o0, o1);                                        \
    if (STG) STAGE_A(PSL, KO);                                                 \
    __builtin_amdgcn_s_barrier();                                              \
    asm volatile("s_waitcnt lgkmcnt(0)"                                        \
                 : "+v"(a0l), "+v"(a0h), "+v"(a1l), "+v"(a1h),                 \
                   "+v"(b0l), "+v"(b0h), "+v"(b1l), "+v"(b1h)                  \
                 :: "memory");                                                 \
    __builtin_amdgcn_sched_barrier(0);                                         \
    intx8 a0 = cat8(a0l, a0h), a1 = cat8(a1l, a1h);                            \
    intx8 b0 = cat8(b0l, b0h), b1 = cat8(b1l, b1h);                            \
    __builtin_amdgcn_s_setprio(1);                                             \
    MFMA(acc[0][0], a0, b0);  MFMA(acc[1][0], a1, b0);                         \
    MFMA(acc[0][1], a0, b1);  MFMA(acc[1][1], a1, b1);                         \
    __builtin_amdgcn_s_setprio(0);                                             \
    __builtin_amdgcn_s_barrier();                                              \
    /* ---- phase 2: frags + B-half stage, quadrant acc[2..3][*] ---- */       \
    DSR2(a2l, a2h, bA_ + 4096, o0, o1);                                        \
    DSR2(a3l, a3h, bA_ + 6144, o0, o1);                                        \
    if (STG) STAGE_B(PSL, KO);                                                 \
    VM;                                                                        \
    __builtin_amdgcn_s_barrier();                                              \
    asm volatile("s_waitcnt lgkmcnt(0)"                                        \
                 : "+v"(a2l), "+v"(a2h), "+v"(a3l), "+v"(a3h)                  \
                 :: "memory");                                                 \
    __builtin_amdgcn_sched_barrier(0);                                         \
    intx8 a2 = cat8(a2l, a2h), a3 = cat8(a3l, a3h);                            \
    __builtin_amdgcn_s_setprio(1);                                             \
    MFMA(acc[2][0], a2, b0);  MFMA(acc[3][0], a3, b0);                         \
    MFMA(acc[2][1], a2, b1);  MFMA(acc[3][1], a3, b1);                         \
    __builtin_amdgcn_s_setprio(0);                                             \
    __builtin_amdgcn_s_barrier();                                              \
  } while (0)

__global__ __launch_bounds__(512) void gemm_max_kernel(
    const unsigned char* __restrict__ A,   // exn [Nx x 768] fp8
    const unsigned char* __restrict__ B,   // eyn [Ny x 768] fp8
    float* __restrict__ partial,           // [ncb][Nx]
    int Nx) {
  __shared__ unsigned char lds[3 * SLOT];  // 96 KB ring
  __shared__ float red[4][BM];             // 4 KB
  lds3 L = (lds3)lds;

  const int tid  = threadIdx.x;
  const int wave = tid >> 6;       // 0..7
  const int lane = tid & 63;
  const int wm = wave >> 2;        // 0..1: 128-row half
  const int wn = wave & 3;         // 0..3: 64-col quarter
  const int l31 = lane & 31;
  const int h   = lane >> 5;       // half-wave: K 32B-half selector

  // T1: supertile XCD swizzle (R3-verified). Concurrent 32 blocks per XCD
  // form an 8(bx) x 4(by) supertile: ~2.3 MB < 4 MB XCD L2. Bijective.
  const int lid    = blockIdx.x;
  const int xcd    = lid & 7;
  const int idx    = lid >> 3;       // 0..255
  const int g      = idx >> 5;       // 0..7
  const int within = idx & 31;
  const int st     = g * 8 + xcd;    // 0..63
  const int bx = (st & 3) * 8 + (within & 7);    // 0..31
  const int by = (st >> 2) * 4 + (within >> 3);  // 0..63

  const int bm0 = bx * BM;
  const int bn0 = by * BN;

  floatx16 acc[4][2];
  #pragma unroll
  for (int m = 0; m < 4; ++m)
    #pragma unroll
    for (int n = 0; n < 2; ++n)
      acc[m][n] = (floatx16)(0.f);

  // reader-side paired-row addresses (R3-verified):
  // addr = (l31>>1)*128 + ((((l31&1)*4 + c) ^ ((l31>>1)&7))*16, c in {2h,2h+1}
  const int key  = (l31 >> 1) & 7;
  const int lrow = (l31 >> 1) * 128;
  const int c0   = 2 * h;
  const int o0 = lrow + ((((l31 & 1) << 2) | c0)       ^ key) * 16;
  const int o1 = lrow + ((((l31 & 1) << 2) | (c0 + 1)) ^ key) * 16;

  // stager (R3-verified inverse): lane q -> phys row q>>3, slot q&7;
  // global source ls = (q&7)^(q>>3); row = 2*(q>>3)+(ls>>2); chunk = ls&3.
  const int ls   = (lane & 7) ^ (lane >> 3);
  const int srow = 2 * (lane >> 3) + (ls >> 2);
  const int sc   = ls & 3;
  const unsigned char* gA = A + (size_t)(bm0 + wave * 32 + srow) * D_DIM + sc * 16;
  const unsigned char* gB = B + (size_t)(bn0 + wave * 32 + srow) * D_DIM + sc * 16;
  const size_t g16 = (size_t)16 * D_DIM;

  STAGE_A(0, 0);      STAGE_B(0, 0);       // tile 0
  STAGE_A(1, BK);     STAGE_B(1, BK);      // tile 1
  VMW(4);                                   // tile 0 resident, tile 1 in flight
  __builtin_amdgcn_s_barrier();

  #pragma unroll 1
  for (int t0 = 0; t0 < 9; t0 += 3) {
    const int kb = t0 * BK;
    TILE(0, 2, kb + 2 * BK, 1, VMW(4));
    TILE(1, 0, kb + 3 * BK, 1, VMW(4));
    TILE(2, 1, kb + 4 * BK, 1, VMW(4));
  }
  TILE(0, 2, 11 * BK, 1, VMW(4));          // t=9: stage tile 11
  TILE(1, 0, 0,       0, VMW(0));          // t=10: drain tile 11's loads
  TILE(2, 0, 0,       0, ((void)0));       // t=11

  // epilogue: per-row max over this block's 256 columns.
  // C/D (32x32): col = l31 (+n*32 + wn*64), row = (reg&3)+8*(reg>>2)+4*h
  // (+m*32 + wm*128)
  #pragma unroll
  for (int m = 0; m < 4; ++m) {
    #pragma unroll
    for (int reg = 0; reg < 16; ++reg) {
      float v = fmaxf(acc[m][0][reg], acc[m][1][reg]);
      #pragma unroll
      for (int off = 1; off < 32; off <<= 1)
        v = fmaxf(v, __shfl_xor(v, off, 64));   // reduce within each 32-half
      if (l31 == 0) {
        int r = wm * 128 + m * 32 + (reg & 3) + 8 * (reg >> 2) + 4 * h;
        red[wn][r] = v;
      }
    }
  }
  __syncthreads();
  if (tid < BM) {
    float mv = fmaxf(fmaxf(red[0][tid], red[1][tid]),
                     fmaxf(red[2][tid], red[3][tid]));
    partial[(size_t)by * Nx + bm0 + tid] = mv;
  }
}

// ---- kernel 3: row max over column blocks + halfnormal transform + block sum

__global__ __launch_bounds__(256) void rowmax_kernel(
    const float* __restrict__ partial, float* __restrict__ bsum, int Nx, int ncb) {
  __shared__ float sdata[4];
  int r = blockIdx.x * blockDim.x + threadIdx.x;
  float m = -1e30f;
  for (int cb = 0; cb < ncb; ++cb)
    m = fmaxf(m, partial[(size_t)cb * Nx + r]);
  float x = 1.0f - m;
  const float logc = -0.22579135264472744f;  // 0.5*log(2/pi), sigma=1
  float l = logc - 0.5f * x * x;
  float t = -__expf(l) * l;
  #pragma unroll
  for (int off = 32; off > 0; off >>= 1) t += __shfl_xor(t, off, 64);
  int wave = threadIdx.x >> 6;
  int lane = threadIdx.x & 63;
  if (lane == 0) sdata[wave] = t;
  __syncthreads();
  if (threadIdx.x == 0)
    bsum[blockIdx.x] = sdata[0] + sdata[1] + sdata[2] + sdata[3];
}

// ---- kernel 4: final sum of block partials -> out[0], out[1] ----------------

__global__ __launch_bounds__(64) void final_kernel(
    const float* __restrict__ bsum, float* __restrict__ out, int nb) {
  int lane = threadIdx.x;
  float s = (lane < nb) ? bsum[lane] : 0.f;
  #pragma unroll
  for (int off = 32; off > 0; off >>= 1) s += __shfl_xor(s, off, 64);
  if (lane == 0) { out[0] = s; out[1] = s; }
}

// ---- launch -----------------------------------------------------------------

extern "C" void kernel_launch(void* const* d_in, const int* in_sizes, int n_in,
                              void* d_out, int out_size, void* d_ws, size_t ws_size,
                              hipStream_t stream) {
  const float* ex = (const float*)d_in[0];
  const float* ey = (const float*)d_in[1];
  const int Nx = in_sizes[0] / D_DIM;   // 8192
  const int Ny = in_sizes[1] / D_DIM;   // 16384
  const int ncb = Ny / BN;              // 64

  char* ws = (char*)d_ws;
  unsigned char* exn = (unsigned char*)ws;                                   // Nx*768 fp8
  unsigned char* eyn = exn + (size_t)Nx * D_DIM;                             // Ny*768 fp8
  float* partial = (float*)(ws + (size_t)(Nx + Ny) * D_DIM);                 // ncb*Nx f32
  float* bsum    = partial + (size_t)ncb * Nx;                               // 32 f32

  norm_cast_kernel<<<(Nx + Ny) / 4, 256, 0, stream>>>(
      ex, ey, (unsigned int*)exn, (unsigned int*)eyn, Nx);
  gemm_max_kernel<<<NBX * NBY, 512, 0, stream>>>(exn, eyn, partial, Nx);
  rowmax_kernel<<<Nx / 256, 256, 0, stream>>>(partial, bsum, Nx, ncb);
  final_kernel<<<1, 64, 0, stream>>>(bsum, (float*)d_out, Nx / 256);
}